// Round 8
// baseline (293.458 us; speedup 1.0000x reference)
//
#include <hip/hip_runtime.h>
#include <math.h>

#define T_DIM 2048
#define D_DIM 2048
#define NHEAD 16
#define DHEAD 128

typedef short v8s __attribute__((ext_vector_type(8)));   // 8 bf16 bit patterns
typedef float v4f __attribute__((ext_vector_type(4)));
typedef unsigned short ush;

#define MFMA16(a, b, c) __builtin_amdgcn_mfma_f32_16x16x32_bf16((a), (b), (c), 0, 0, 0)

__device__ __forceinline__ ush f2bf(float f) {
    unsigned u = __float_as_uint(f);
    u += 0x7FFF + ((u >> 16) & 1);          // RNE
    return (ush)(u >> 16);
}
__device__ __forceinline__ float bf2f(ush h) {
    return __uint_as_float((unsigned)h << 16);
}
__device__ __forceinline__ unsigned pack2(ush a, ush b) {
    return (unsigned)a | ((unsigned)b << 16);
}

__device__ __forceinline__ void gload_lds16(const ush* g, ush* l) {
    __builtin_amdgcn_global_load_lds(
        (const __attribute__((address_space(1))) void*)g,
        (__attribute__((address_space(3))) void*)l, 16, 0, 0);
}

// ---------------------------------------------------------------------------
// split fp32 -> bf16 hi/lo. Single-matrix version (fallback path).
// ---------------------------------------------------------------------------
__global__ __launch_bounds__(256) void split_x(
    const float* __restrict__ X, ush* __restrict__ Xh, ush* __restrict__ Xl)
{
    const int i = (blockIdx.x * 256 + threadIdx.x) * 8;
    const float4 a = *(const float4*)&X[i];
    const float4 b = *(const float4*)&X[i + 4];
    const float f[8] = {a.x, a.y, a.z, a.w, b.x, b.y, b.z, b.w};
    ush h[8], l[8];
#pragma unroll
    for (int e = 0; e < 8; ++e) {
        h[e] = f2bf(f[e]);
        l[e] = f2bf(f[e] - bf2f(h[e]));
    }
    uint4 hv, lv;
    hv.x = pack2(h[0], h[1]); hv.y = pack2(h[2], h[3]);
    hv.z = pack2(h[4], h[5]); hv.w = pack2(h[6], h[7]);
    lv.x = pack2(l[0], l[1]); lv.y = pack2(l[2], l[3]);
    lv.z = pack2(l[4], l[5]); lv.w = pack2(l[6], l[7]);
    *(uint4*)&Xh[i] = hv;
    *(uint4*)&Xl[i] = lv;
}

// Fused 5-matrix split (x, Wq, Wk, Wv, Wo) — one launch.
struct Split5Args { const float* s[5]; ush* h[5]; ush* l[5]; };

__global__ __launch_bounds__(256) void split5(Split5Args a)
{
    const int m = blockIdx.y;
    const float* X = a.s[m];
    ush* Xh = a.h[m];
    ush* Xl = a.l[m];
    const int i = (blockIdx.x * 256 + threadIdx.x) * 8;
    const float4 p = *(const float4*)&X[i];
    const float4 q = *(const float4*)&X[i + 4];
    const float f[8] = {p.x, p.y, p.z, p.w, q.x, q.y, q.z, q.w};
    ush h[8], l[8];
#pragma unroll
    for (int e = 0; e < 8; ++e) {
        h[e] = f2bf(f[e]);
        l[e] = f2bf(f[e] - bf2f(h[e]));
    }
    uint4 hv, lv;
    hv.x = pack2(h[0], h[1]); hv.y = pack2(h[2], h[3]);
    hv.z = pack2(h[4], h[5]); hv.w = pack2(h[6], h[7]);
    lv.x = pack2(l[0], l[1]); lv.y = pack2(l[2], l[3]);
    lv.z = pack2(l[4], l[5]); lv.w = pack2(l[6], l[7]);
    *(uint4*)&Xh[i] = hv;
    *(uint4*)&Xl[i] = lv;
}

// ---------------------------------------------------------------------------
// GEMM C = A @ B^T + bias, bf16x3. Round-8: DOUBLE-BUFFERED staging with
// counted vmcnt (T3/T4): stage(t+1) issued before compute(t); vmcnt(6)
// waits only tile t's loads (never drains the pipeline); raw s_barrier x2.
// LDS 2 x 48 KB = 96 KB dynamic -> 1 block/CU, loads in flight a full tile.
// ---------------------------------------------------------------------------
template <int MODE>
__global__ __launch_bounds__(512, 2) void gemm_x3(
    const ush* __restrict__ Ahg, const ush* __restrict__ Alg,
    const ush* __restrict__ Bhg, const ush* __restrict__ Blg,
    const float* __restrict__ bias, float scale,
    ush* __restrict__ Ob, float* __restrict__ Of)
{
    extern __shared__ ush xsmem[];       // 2 buffers x 24576 ush (48 KB)

    const int tid = threadIdx.x;
    const int l   = tid & 63;
    const int wid = tid >> 6;
    const int wm  = wid >> 1;
    const int wn  = wid & 1;
    const int cl  = l & 15;
    const int rg  = l >> 4;

    const int bid     = blockIdx.x;
    const int logical = (bid & 7) * 64 + (bid >> 3);
    const int m0      = (logical >> 5) * 128;
    const int n0      = (logical & 31) * 64;

    const int arow = tid >> 3;
    const int achk = tid & 7;
    const int axor = (achk ^ (arow & 7)) * 8;

    auto stage = [&](ush* buf, int k0) {   // 6 gload_lds per thread
        ush* Ah = buf;
        ush* Al = buf + 8192;
        ush* Bh = buf + 16384;
        ush* Bl = buf + 20480;
        gload_lds16(&Ahg[(size_t)(m0 + arow) * D_DIM + k0 + axor],      &Ah[tid * 8]);
        gload_lds16(&Ahg[(size_t)(m0 + arow + 64) * D_DIM + k0 + axor], &Ah[(tid + 512) * 8]);
        gload_lds16(&Alg[(size_t)(m0 + arow) * D_DIM + k0 + axor],      &Al[tid * 8]);
        gload_lds16(&Alg[(size_t)(m0 + arow + 64) * D_DIM + k0 + axor], &Al[(tid + 512) * 8]);
        gload_lds16(&Bhg[(size_t)(n0 + arow) * D_DIM + k0 + axor],      &Bh[tid * 8]);
        gload_lds16(&Blg[(size_t)(n0 + arow) * D_DIM + k0 + axor],      &Bl[tid * 8]);
    };

    v4f acc[2][2];
#pragma unroll
    for (int i = 0; i < 2; ++i)
#pragma unroll
        for (int j = 0; j < 2; ++j) acc[i][j] = (v4f)0.f;

    constexpr int NT = D_DIM / 64;       // 32
    stage(xsmem, 0);

    for (int ks = 0; ks < NT; ++ks) {
        ush* cbuf = xsmem + (ks & 1) * 24576;
        ush* nbuf = xsmem + ((ks & 1) ^ 1) * 24576;
        if (ks + 1 < NT) {
            stage(nbuf, (ks + 1) * 64);
            asm volatile("s_waitcnt vmcnt(6)" ::: "memory");   // tile ks landed
        } else {
            asm volatile("s_waitcnt vmcnt(0)" ::: "memory");
        }
        __builtin_amdgcn_s_barrier();    // tile ks visible to all waves

        ush* Ah = cbuf;
        ush* Al = cbuf + 8192;
        ush* Bh = cbuf + 16384;
        ush* Bl = cbuf + 20480;
#pragma unroll
        for (int kf = 0; kf < 2; ++kf) {
            const int c = kf * 4 + rg;
            v8s a_h[2], a_l[2], b_h[2], b_l[2];
#pragma unroll
            for (int mf = 0; mf < 2; ++mf) {
                const int r = wm * 32 + mf * 16 + cl;
                const int off = r * 64 + ((c ^ (r & 7)) * 8);
                a_h[mf] = *(const v8s*)&Ah[off];
                a_l[mf] = *(const v8s*)&Al[off];
            }
#pragma unroll
            for (int nf = 0; nf < 2; ++nf) {
                const int r = wn * 32 + nf * 16 + cl;
                const int off = r * 64 + ((c ^ (r & 7)) * 8);
                b_h[nf] = *(const v8s*)&Bh[off];
                b_l[nf] = *(const v8s*)&Bl[off];
            }
#pragma unroll
            for (int mf = 0; mf < 2; ++mf)
#pragma unroll
                for (int nf = 0; nf < 2; ++nf) {
                    acc[mf][nf] = MFMA16(a_h[mf], b_h[nf], acc[mf][nf]);
                    acc[mf][nf] = MFMA16(a_h[mf], b_l[nf], acc[mf][nf]);
                    acc[mf][nf] = MFMA16(a_l[mf], b_h[nf], acc[mf][nf]);
                }
        }
        asm volatile("" ::: "memory");
        __builtin_amdgcn_s_barrier();    // all waves done reading cbuf
    }

#pragma unroll
    for (int mf = 0; mf < 2; ++mf)
#pragma unroll
        for (int nf = 0; nf < 2; ++nf) {
            const int n  = n0 + wn * 32 + nf * 16 + cl;
            const int mb = m0 + wm * 32 + mf * 16 + rg * 4;
            const float bv = bias[n];
            if (MODE == 0) {
#pragma unroll
                for (int j = 0; j < 4; ++j)
                    Ob[(size_t)(mb + j) * D_DIM + n] =
                        f2bf((acc[mf][nf][j] + bv) * scale);
            } else if (MODE == 1) {
                ushort4 pk;
                pk.x = f2bf(acc[mf][nf][0] + bv);
                pk.y = f2bf(acc[mf][nf][1] + bv);
                pk.z = f2bf(acc[mf][nf][2] + bv);
                pk.w = f2bf(acc[mf][nf][3] + bv);
                *(ushort4*)&Ob[(size_t)n * D_DIM + mb] = pk;   // Vt[n][m..m+3]
            } else {
#pragma unroll
                for (int j = 0; j < 4; ++j)
                    Of[(size_t)(mb + j) * D_DIM + n] = acc[mf][nf][j] + bv;
            }
        }
}

// ---------------------------------------------------------------------------
// FUSED QKV GEMM, bf16x3, hi|lo interleaved rows (conflict-free, round 7).
// Round-8: DOUBLE-BUFFERED counted-vmcnt pipeline, 2 x 40 KB = 80 KB LDS.
// ---------------------------------------------------------------------------
__global__ __launch_bounds__(512, 2) void gemm_qkv(
    const ush* __restrict__ xh, const ush* __restrict__ xl,
    const ush* __restrict__ Wqh, const ush* __restrict__ Wql,
    const ush* __restrict__ Wkh, const ush* __restrict__ Wkl,
    const ush* __restrict__ Wvh, const ush* __restrict__ Wvl,
    const float* __restrict__ bq, const float* __restrict__ bk,
    const float* __restrict__ bv, float qscale,
    ush* __restrict__ Qo, ush* __restrict__ Ko, ush* __restrict__ Vto)
{
    extern __shared__ ush qsmem[];       // 2 buffers x 20480 ush (40 KB)

    const int tid = threadIdx.x;
    const int l   = tid & 63;
    const int wid = tid >> 6;
    const int wm  = wid >> 1;      // 0..3
    const int wn  = wid & 1;       // 0..1
    const int cl  = l & 15;
    const int rg  = l >> 4;

    const int bid     = blockIdx.x;
    const int logical = (bid & 7) * 64 + (bid >> 3);
    const int m0      = (logical >> 5) * 128;
    const int n0      = (logical & 31) * 64;

    const ush* Wh[3] = {Wqh, Wkh, Wvh};
    const ush* Wl[3] = {Wql, Wkl, Wvl};

    auto stage = [&](ush* buf, int k0) {   // 5 gload_lds per thread
        ush* As = buf;
        ush* Bs = buf + 8192;
#pragma unroll
        for (int i = 0; i < 2; ++i) {
            const int p   = i * 512 + tid;
            const int row = p >> 3;
            const int lc  = (p & 7) ^ (row & 7);
            const ush* src = (lc < 4 ? xh : xl) +
                             (size_t)(m0 + row) * D_DIM + k0 + (lc & 3) * 8;
            gload_lds16(src, &As[p * 8]);
        }
        {
            const int p   = tid;
            const int row = p >> 3;
            const int lc  = (p & 7) ^ (row & 7);
            const size_t off = (size_t)(n0 + row) * D_DIM + k0 + (lc & 3) * 8;
#pragma unroll
            for (int wg = 0; wg < 3; ++wg)
                gload_lds16((lc < 4 ? Wh[wg] : Wl[wg]) + off,
                            &Bs[wg * 4096 + p * 8]);
        }
    };

    v4f acc[3][2][2];
#pragma unroll
    for (int wg = 0; wg < 3; ++wg)
#pragma unroll
        for (int i = 0; i < 2; ++i)
#pragma unroll
            for (int j = 0; j < 2; ++j) acc[wg][i][j] = (v4f)0.f;

    constexpr int NT = D_DIM / 32;       // 64
    stage(qsmem, 0);

    for (int ks = 0; ks < NT; ++ks) {
        ush* cbuf = qsmem + (ks & 1) * 20480;
        ush* nbuf = qsmem + ((ks & 1) ^ 1) * 20480;
        if (ks + 1 < NT) {
            stage(nbuf, (ks + 1) * 32);
            asm volatile("s_waitcnt vmcnt(5)" ::: "memory");   // tile ks landed
        } else {
            asm volatile("s_waitcnt vmcnt(0)" ::: "memory");
        }
        __builtin_amdgcn_s_barrier();    // tile ks visible to all waves

        ush* As = cbuf;
        v8s a_h[2], a_l[2];
#pragma unroll
        for (int mf = 0; mf < 2; ++mf) {
            const int r = wm * 32 + mf * 16 + cl;
            a_h[mf] = *(const v8s*)&As[r * 64 + ((rg ^ (r & 7)) * 8)];
            a_l[mf] = *(const v8s*)&As[r * 64 + (((rg + 4) ^ (r & 7)) * 8)];
        }
#pragma unroll
        for (int wg = 0; wg < 3; ++wg) {
            const ush* Bw = cbuf + 8192 + wg * 4096;
            v8s b_h[2], b_l[2];
#pragma unroll
            for (int nf = 0; nf < 2; ++nf) {
                const int r = wn * 32 + nf * 16 + cl;
                b_h[nf] = *(const v8s*)&Bw[r * 64 + ((rg ^ (r & 7)) * 8)];
                b_l[nf] = *(const v8s*)&Bw[r * 64 + (((rg + 4) ^ (r & 7)) * 8)];
            }
#pragma unroll
            for (int mf = 0; mf < 2; ++mf)
#pragma unroll
                for (int nf = 0; nf < 2; ++nf) {
                    acc[wg][mf][nf] = MFMA16(a_h[mf], b_h[nf], acc[wg][mf][nf]);
                    acc[wg][mf][nf] = MFMA16(a_h[mf], b_l[nf], acc[wg][mf][nf]);
                    acc[wg][mf][nf] = MFMA16(a_l[mf], b_h[nf], acc[wg][mf][nf]);
                }
        }
        asm volatile("" ::: "memory");
        __builtin_amdgcn_s_barrier();    // all waves done reading cbuf
    }

    // epilogue: Q scaled row-major, K row-major, V transposed
#pragma unroll
    for (int mf = 0; mf < 2; ++mf)
#pragma unroll
        for (int nf = 0; nf < 2; ++nf) {
            const int n  = n0 + wn * 32 + nf * 16 + cl;
            const int mb = m0 + wm * 32 + mf * 16 + rg * 4;
            const float bvq = bq[n], bvk = bk[n], bvv = bv[n];
#pragma unroll
            for (int j = 0; j < 4; ++j) {
                Qo[(size_t)(mb + j) * D_DIM + n] =
                    f2bf((acc[0][mf][nf][j] + bvq) * qscale);
                Ko[(size_t)(mb + j) * D_DIM + n] =
                    f2bf(acc[1][mf][nf][j] + bvk);
            }
            ushort4 pk;
            pk.x = f2bf(acc[2][mf][nf][0] + bvv);
            pk.y = f2bf(acc[2][mf][nf][1] + bvv);
            pk.z = f2bf(acc[2][mf][nf][2] + bvv);
            pk.w = f2bf(acc[2][mf][nf][3] + bvv);
            *(ushort4*)&Vto[(size_t)n * D_DIM + mb] = pk;
        }
}

// ---------------------------------------------------------------------------
// Causal flash attention, bf16 MFMA, in-block KV split, swapped operands.
// LDS 64 KB (Ps overlaid on Ks[0:8KB]) -> 2 blocks/CU. (proven — unchanged)
// ---------------------------------------------------------------------------
__global__ __launch_bounds__(512, 4) void attn_fused(
    const ush* __restrict__ Qg, const ush* __restrict__ Kg,
    const ush* __restrict__ Vtg,
    ush* __restrict__ Yh, ush* __restrict__ Yl)
{
    extern __shared__ char smem[];
    const int b   = blockIdx.x;
    const int h   = b & 15;
    const int qt  = 31 - (b >> 4);       // descending: long blocks first
    const int q0  = qt * 64;
    const int tid = threadIdx.x;
    const int l   = tid & 63;
    const int wid = tid >> 6;
    const int grp = wid >> 2;            // 0 or 1
    const int w   = wid & 3;             // wave: q rows [w*16, w*16+16)
    const int cl  = l & 15;
    const int rg  = l >> 4;
    const int clx = cl & 7;
    const int tg  = tid & 255;

    char* gbase = smem + grp * 32768;
    ush* Ks = (ush*)gbase;               // [64][128] swz, 16 KB
    ush* Vs = (ush*)(gbase + 16384);     // [128][64] swz, 16 KB
    ush* Ps = Ks;                        // overlaid on Ks[0:8KB]

    const int split = (qt + 2) >> 1;
    const int iters = split;
    const int t0    = grp ? split : 0;
    const int tcnt  = grp ? (qt + 1 - split) : split;

    const int qrow = q0 + w * 16 + cl;

    v8s qf[4];
#pragma unroll
    for (int kf = 0; kf < 4; ++kf)
        qf[kf] = *(const v8s*)&Qg[(size_t)qrow * D_DIM + h * DHEAD + kf * 32 + rg * 8];

    v4f acc[8];
#pragma unroll
    for (int nf = 0; nf < 8; ++nf) acc[nf] = (v4f)0.f;
    float mrow = -INFINITY;
    float lsum = 0.f;

    auto stage = [&](int tile) {
#pragma unroll
        for (int i = 0; i < 4; ++i) {
            const int id = i * 256 + tg;
            const int kr = id >> 4, kc = id & 15;
            gload_lds16(&Kg[(size_t)(tile * 64 + kr) * D_DIM + h * DHEAD +
                            ((kc ^ (kr & 7)) * 8)], &Ks[id * 8]);
        }
#pragma unroll
        for (int i = 0; i < 4; ++i) {
            const int id = i * 256 + tg;
            const int vr = id >> 3, vc = id & 7;
            gload_lds16(&Vtg[(size_t)(h * DHEAD + vr) * D_DIM + tile * 64 +
                             ((vc ^ (vr & 7)) * 8)], &Vs[id * 8]);
        }
    };

    for (int t = 0; t < iters; ++t) {
        __syncthreads();                 // prev tile's Ks/Vs/Ps reads done
        if (t < tcnt) stage(t0 + t);
        __syncthreads();                 // staged data valid
        const bool act = (t < tcnt);
        const int tile = t0 + t;
        uint2 pk[4];
        if (act) {
            v4f st[4];
#pragma unroll
            for (int n = 0; n < 4; ++n) st[n] = (v4f)0.f;
            __builtin_amdgcn_s_setprio(1);
#pragma unroll
            for (int kf = 0; kf < 4; ++kf) {
#pragma unroll
                for (int n = 0; n < 4; ++n) {
                    const v8s kfr = *(const v8s*)&Ks[(n * 16 + cl) * 128 +
                                     (((kf * 4 + rg) ^ clx) * 8)];
                    st[n] = MFMA16(kfr, qf[kf], st[n]);
                }
            }
            __builtin_amdgcn_s_setprio(0);

            float sv[4][4];
            const bool dm = (tile == qt);
#pragma unroll
            for (int n = 0; n < 4; ++n)
#pragma unroll
                for (int jj = 0; jj < 4; ++jj) {
                    float v = st[n][jj];
                    if (dm && (tile * 64 + n * 16 + rg * 4 + jj > qrow))
                        v = -INFINITY;
                    sv[n][jj] = v;
                }
            float mx = sv[0][0];
#pragma unroll
            for (int n = 0; n < 4; ++n)
#pragma unroll
                for (int jj = 0; jj < 4; ++jj) mx = fmaxf(mx, sv[n][jj]);
            mx = fmaxf(mx, __shfl_xor(mx, 16));
            mx = fmaxf(mx, __shfl_xor(mx, 32));
            const float mnew = fmaxf(mrow, mx);

            float rs = 0.f;
#pragma unroll
            for (int n = 0; n < 4; ++n) {
                float p0 = exp2f(sv[n][0] - mnew);
                float p1 = exp2f(sv[n][1] - mnew);
                float p2 = exp2f(sv[n][2] - mnew);
                float p3 = exp2f(sv[n][3] - mnew);
                rs += (p0 + p1) + (p2 + p3);
                pk[n].x = pack2(f2bf(p0), f2bf(p1));
                pk[n].y = pack2(f2bf(p2), f2bf(p3));
            }
            rs += __shfl_xor(rs, 16);
            rs += __shfl_xor(rs, 32);

            const float corr = exp2f(mrow - mnew);
            lsum = lsum * corr + rs;
            mrow = mnew;
#pragma unroll
            for (int nf = 0; nf < 8; ++nf) acc[nf] *= corr;
        }
        __syncthreads();                 // all Ks reads done -> Ps may overwrite
        if (act) {
#pragma unroll
            for (int n = 0; n < 4; ++n)
                *(uint2*)&Ps[(w * 16 + cl) * 64 +
                             (((2 * n + (rg >> 1)) ^ clx) * 8) + (rg & 1) * 4] = pk[n];
            const int pr = w * 16 + cl;
            v8s pa[2];
            pa[0] = *(const v8s*)&Ps[pr * 64 + ((rg ^ clx) * 8)];
            pa[1] = *(const v8s*)&Ps[pr * 64 + (((4 + rg) ^ clx) * 8)];
            __builtin_amdgcn_s_setprio(1);
#pragma unroll
            for (int nf = 0; nf < 8; ++nf) {
#pragma unroll
                for (int kk = 0; kk < 2; ++kk) {
                    const v8s vb = *(const v8s*)&Vs[(nf * 16 + cl) * 64 +
                                    (((kk * 4 + rg) ^ clx) * 8)];
                    acc[nf] = MFMA16(vb, pa[kk], acc[nf]);
                }
            }
            __builtin_amdgcn_s_setprio(0);
        }
    }

    // ---- in-LDS merge of the two KV-half partials (lane-local in q) ----
    float* mAcc = (float*)smem;              // [64][132] fp32, 33792 B
    float* mML  = (float*)(smem + 33792);    // [64][2]

    const int lr = w * 16 + cl;
    __syncthreads();                         // all compute done
    if (grp == 1) {
#pragma unroll
        for (int nf = 0; nf < 8; ++nf)
            *(v4f*)&mAcc[lr * 132 + nf * 16 + rg * 4] = acc[nf];
        if (rg == 0) {
            mML[lr * 2]     = mrow;
            mML[lr * 2 + 1] = lsum;
        }
    }
    __syncthreads();
    if (grp == 0) {
        const float m1 = mML[lr * 2];
        const float l1 = mML[lr * 2 + 1];
        const float ms = fmaxf(mrow, m1);
        const float e0 = exp2f(mrow - ms);
        const float e1 = exp2f(m1 - ms);
        const float inv = 1.0f / (lsum * e0 + l1 * e1);
        const float s0 = e0 * inv, s1 = e1 * inv;
#pragma unroll
        for (int nf = 0; nf < 8; ++nf) {
            const v4f a1 = *(const v4f*)&mAcc[lr * 132 + nf * 16 + rg * 4];
            float y[4];
#pragma unroll
            for (int j = 0; j < 4; ++j) y[j] = acc[nf][j] * s0 + a1[j] * s1;
            ushort4 ph, pl;
            ush hh;
            hh = f2bf(y[0]); ph.x = hh; pl.x = f2bf(y[0] - bf2f(hh));
            hh = f2bf(y[1]); ph.y = hh; pl.y = f2bf(y[1] - bf2f(hh));
            hh = f2bf(y[2]); ph.z = hh; pl.z = f2bf(y[2] - bf2f(hh));
            hh = f2bf(y[3]); ph.w = hh; pl.w = f2bf(y[3] - bf2f(hh));
            const size_t o = (size_t)(q0 + lr) * D_DIM + h * DHEAD + nf * 16 + rg * 4;
            *(ushort4*)&Yh[o] = ph;
            *(ushort4*)&Yl[o] = pl;
        }
    }
}

// ---------------------------------------------------------------------------
extern "C" void kernel_launch(void* const* d_in, const int* in_sizes, int n_in,
                              void* d_out, int out_size, void* d_ws, size_t ws_size,
                              hipStream_t stream)
{
    const float* x  = (const float*)d_in[0];
    const float* Wq = (const float*)d_in[1];
    const float* bq = (const float*)d_in[2];
    const float* Wk = (const float*)d_in[3];
    const float* bk = (const float*)d_in[4];
    const float* Wv = (const float*)d_in[5];
    const float* bv = (const float*)d_in[6];
    const float* Wo = (const float*)d_in[7];
    const float* bo = (const float*)d_in[8];
    float* out = (float*)d_out;

    const size_t mat = (size_t)T_DIM * D_DIM;
    // 1/sqrt(128) * log2(e): attention runs in exp2 domain
    const float qscale = 0.08838834764831845f * 1.4426950408889634f;

    const int attn_lds = 65536;
    const int gx3_lds  = 98304;          // 2 x 48 KB
    const int qkv_lds  = 81920;          // 2 x 40 KB
    hipFuncSetAttribute((const void*)attn_fused,
                        hipFuncAttributeMaxDynamicSharedMemorySize, attn_lds);
    hipFuncSetAttribute((const void*)gemm_x3<0>,
                        hipFuncAttributeMaxDynamicSharedMemorySize, gx3_lds);
    hipFuncSetAttribute((const void*)gemm_x3<1>,
                        hipFuncAttributeMaxDynamicSharedMemorySize, gx3_lds);
    hipFuncSetAttribute((const void*)gemm_x3<2>,
                        hipFuncAttributeMaxDynamicSharedMemorySize, gx3_lds);
    hipFuncSetAttribute((const void*)gemm_qkv,
                        hipFuncAttributeMaxDynamicSharedMemorySize, qkv_lds);

    const size_t need_fused = 13 * mat * sizeof(ush);   // 109.1 MB

    if (ws_size >= need_fused) {
        // ---------------- fused path: 4 dispatches ----------------
        ush* xh  = (ush*)d_ws;
        ush* xl  = xh  + mat;
        ush* Qh  = xl  + mat;
        ush* Kh  = Qh  + mat;
        ush* Vth = Kh  + mat;
        ush* Wqh = Vth + mat;
        ush* Wql = Wqh + mat;
        ush* Wkh = Wql + mat;
        ush* Wkl = Wkh + mat;
        ush* Wvh = Wkl + mat;
        ush* Wvl = Wvh + mat;
        ush* Woh = Wvl + mat;
        ush* Wol = Woh + mat;
        ush* Yh  = xh;   // x dead after gemm_qkv
        ush* Yl  = xl;

        Split5Args sa;
        sa.s[0] = x;  sa.h[0] = xh;  sa.l[0] = xl;
        sa.s[1] = Wq; sa.h[1] = Wqh; sa.l[1] = Wql;
        sa.s[2] = Wk; sa.h[2] = Wkh; sa.l[2] = Wkl;
        sa.s[3] = Wv; sa.h[3] = Wvh; sa.l[3] = Wvl;
        sa.s[4] = Wo; sa.h[4] = Woh; sa.l[4] = Wol;
        split5<<<dim3(mat / 2048, 5), 256, 0, stream>>>(sa);

        gemm_qkv<<<512, 512, qkv_lds, stream>>>(
            xh, xl, Wqh, Wql, Wkh, Wkl, Wvh, Wvl, bq, bk, bv, qscale,
            Qh, Kh, Vth);

        attn_fused<<<512, 512, attn_lds, stream>>>(Qh, Kh, Vth, Yh, Yl);

        gemm_x3<2><<<512, 512, gx3_lds, stream>>>(Yh, Yl, Woh, Wol, bo, 1.0f,
                                                  nullptr, out);
    } else {
        // ---------------- fallback: round-5 sequence (same kernels) --------
        ush* xh  = (ush*)d_ws;
        ush* xl  = xh + mat;
        ush* Qh  = xl + mat;
        ush* Kh  = Qh + mat;
        ush* Vth = Kh + mat;
        ush* Wh  = Vth + mat;
        ush* Wl  = Wh + mat;
        ush* Yh  = xh;
        ush* Yl  = xl;

        split_x<<<mat / 2048, 256, 0, stream>>>(x, xh, xl);

        split_x<<<mat / 2048, 256, 0, stream>>>(Wq, Wh, Wl);
        gemm_x3<0><<<512, 512, gx3_lds, stream>>>(xh, xl, Wh, Wl, bq, qscale, Qh, nullptr);
        split_x<<<mat / 2048, 256, 0, stream>>>(Wk, Wh, Wl);
        gemm_x3<0><<<512, 512, gx3_lds, stream>>>(xh, xl, Wh, Wl, bk, 1.0f, Kh, nullptr);
        split_x<<<mat / 2048, 256, 0, stream>>>(Wv, Wh, Wl);
        gemm_x3<1><<<512, 512, gx3_lds, stream>>>(xh, xl, Wh, Wl, bv, 1.0f, Vth, nullptr);

        attn_fused<<<512, 512, attn_lds, stream>>>(Qh, Kh, Vth, Yh, Yl);

        split_x<<<mat / 2048, 256, 0, stream>>>(Wo, Wh, Wl);
        gemm_x3<2><<<512, 512, gx3_lds, stream>>>(Yh, Yl, Wh, Wl, bo, 1.0f, nullptr, out);
    }
}

// Round 9
// 258.790 us; speedup vs baseline: 1.1340x; 1.1340x over previous
//
#include <hip/hip_runtime.h>
#include <math.h>

#define T_DIM 2048
#define D_DIM 2048
#define NHEAD 16
#define DHEAD 128

typedef short v8s __attribute__((ext_vector_type(8)));   // 8 bf16 bit patterns
typedef float v4f __attribute__((ext_vector_type(4)));
typedef unsigned short ush;

#define MFMA16(a, b, c) __builtin_amdgcn_mfma_f32_16x16x32_bf16((a), (b), (c), 0, 0, 0)

__device__ __forceinline__ ush f2bf(float f) {
    unsigned u = __float_as_uint(f);
    u += 0x7FFF + ((u >> 16) & 1);          // RNE
    return (ush)(u >> 16);
}
__device__ __forceinline__ float bf2f(ush h) {
    return __uint_as_float((unsigned)h << 16);
}
__device__ __forceinline__ unsigned pack2(ush a, ush b) {
    return (unsigned)a | ((unsigned)b << 16);
}

__device__ __forceinline__ void gload_lds16(const ush* g, ush* l) {
    __builtin_amdgcn_global_load_lds(
        (const __attribute__((address_space(1))) void*)g,
        (__attribute__((address_space(3))) void*)l, 16, 0, 0);
}

// 2-D region XCD swizzle for a 16(m) x 32(n) grid of 512 blocks.
// Each XCD owns an 8m x 8n region (64 blocks, all co-resident at 2/CU):
// per-XCD compulsory L2 fill drops ~48MB -> ~20MB (A 8MB + B 12MB).
__device__ __forceinline__ void region_swizzle(int bid, int& m0, int& n0) {
    const int xcd = bid & 7;
    const int lg  = bid >> 3;                       // 0..63 within region
    const int mp  = ((xcd >> 2) << 3) + (lg >> 3);  // 0..15
    const int np  = ((xcd & 3) << 3) + (lg & 7);    // 0..31
    m0 = mp * 128;
    n0 = np * 64;
}

// ---------------------------------------------------------------------------
// split fp32 -> bf16 hi/lo. Single-matrix version (fallback path).
// ---------------------------------------------------------------------------
__global__ __launch_bounds__(256) void split_x(
    const float* __restrict__ X, ush* __restrict__ Xh, ush* __restrict__ Xl)
{
    const int i = (blockIdx.x * 256 + threadIdx.x) * 8;
    const float4 a = *(const float4*)&X[i];
    const float4 b = *(const float4*)&X[i + 4];
    const float f[8] = {a.x, a.y, a.z, a.w, b.x, b.y, b.z, b.w};
    ush h[8], l[8];
#pragma unroll
    for (int e = 0; e < 8; ++e) {
        h[e] = f2bf(f[e]);
        l[e] = f2bf(f[e] - bf2f(h[e]));
    }
    uint4 hv, lv;
    hv.x = pack2(h[0], h[1]); hv.y = pack2(h[2], h[3]);
    hv.z = pack2(h[4], h[5]); hv.w = pack2(h[6], h[7]);
    lv.x = pack2(l[0], l[1]); lv.y = pack2(l[2], l[3]);
    lv.z = pack2(l[4], l[5]); lv.w = pack2(l[6], l[7]);
    *(uint4*)&Xh[i] = hv;
    *(uint4*)&Xl[i] = lv;
}

// Fused 5-matrix split (x, Wq, Wk, Wv, Wo) — one launch.
struct Split5Args { const float* s[5]; ush* h[5]; ush* l[5]; };

__global__ __launch_bounds__(256) void split5(Split5Args a)
{
    const int m = blockIdx.y;
    const float* X = a.s[m];
    ush* Xh = a.h[m];
    ush* Xl = a.l[m];
    const int i = (blockIdx.x * 256 + threadIdx.x) * 8;
    const float4 p = *(const float4*)&X[i];
    const float4 q = *(const float4*)&X[i + 4];
    const float f[8] = {p.x, p.y, p.z, p.w, q.x, q.y, q.z, q.w};
    ush h[8], l[8];
#pragma unroll
    for (int e = 0; e < 8; ++e) {
        h[e] = f2bf(f[e]);
        l[e] = f2bf(f[e] - bf2f(h[e]));
    }
    uint4 hv, lv;
    hv.x = pack2(h[0], h[1]); hv.y = pack2(h[2], h[3]);
    hv.z = pack2(h[4], h[5]); hv.w = pack2(h[6], h[7]);
    lv.x = pack2(l[0], l[1]); lv.y = pack2(l[2], l[3]);
    lv.z = pack2(l[4], l[5]); lv.w = pack2(l[6], l[7]);
    *(uint4*)&Xh[i] = hv;
    *(uint4*)&Xl[i] = lv;
}

// ---------------------------------------------------------------------------
// GEMM C = A @ B^T + bias, bf16x3. Round-9: REVERT to round-7 2-phase
// structure (static 48 KB LDS, 2-3 blocks/CU cross-block overlap — round 8's
// dbuf halved residency and doubled L2 fill) + 2-D region XCD swizzle.
// ---------------------------------------------------------------------------
template <int MODE>
__global__ __launch_bounds__(512, 4) void gemm_x3(
    const ush* __restrict__ Ahg, const ush* __restrict__ Alg,
    const ush* __restrict__ Bhg, const ush* __restrict__ Blg,
    const float* __restrict__ bias, float scale,
    ush* __restrict__ Ob, float* __restrict__ Of)
{
    __shared__ ush Ah[128 * 64];
    __shared__ ush Al[128 * 64];
    __shared__ ush Bh[64 * 64];
    __shared__ ush Bl[64 * 64];

    const int tid = threadIdx.x;
    const int l   = tid & 63;
    const int wid = tid >> 6;
    const int wm  = wid >> 1;
    const int wn  = wid & 1;
    const int cl  = l & 15;
    const int rg  = l >> 4;

    int m0, n0;
    region_swizzle(blockIdx.x, m0, n0);

    const int arow = tid >> 3;
    const int achk = tid & 7;
    const int axor = (achk ^ (arow & 7)) * 8;

    v4f acc[2][2];
#pragma unroll
    for (int i = 0; i < 2; ++i)
#pragma unroll
        for (int j = 0; j < 2; ++j) acc[i][j] = (v4f)0.f;

    for (int ks = 0; ks < D_DIM / 64; ++ks) {
        const int k0 = ks * 64;
        __syncthreads();
        gload_lds16(&Ahg[(size_t)(m0 + arow) * D_DIM + k0 + axor],      &Ah[tid * 8]);
        gload_lds16(&Ahg[(size_t)(m0 + arow + 64) * D_DIM + k0 + axor], &Ah[(tid + 512) * 8]);
        gload_lds16(&Alg[(size_t)(m0 + arow) * D_DIM + k0 + axor],      &Al[tid * 8]);
        gload_lds16(&Alg[(size_t)(m0 + arow + 64) * D_DIM + k0 + axor], &Al[(tid + 512) * 8]);
        gload_lds16(&Bhg[(size_t)(n0 + arow) * D_DIM + k0 + axor],      &Bh[tid * 8]);
        gload_lds16(&Blg[(size_t)(n0 + arow) * D_DIM + k0 + axor],      &Bl[tid * 8]);
        __syncthreads();

#pragma unroll
        for (int kf = 0; kf < 2; ++kf) {
            const int c = kf * 4 + rg;
            v8s a_h[2], a_l[2], b_h[2], b_l[2];
#pragma unroll
            for (int mf = 0; mf < 2; ++mf) {
                const int r = wm * 32 + mf * 16 + cl;
                const int off = r * 64 + ((c ^ (r & 7)) * 8);
                a_h[mf] = *(const v8s*)&Ah[off];
                a_l[mf] = *(const v8s*)&Al[off];
            }
#pragma unroll
            for (int nf = 0; nf < 2; ++nf) {
                const int r = wn * 32 + nf * 16 + cl;
                const int off = r * 64 + ((c ^ (r & 7)) * 8);
                b_h[nf] = *(const v8s*)&Bh[off];
                b_l[nf] = *(const v8s*)&Bl[off];
            }
#pragma unroll
            for (int mf = 0; mf < 2; ++mf)
#pragma unroll
                for (int nf = 0; nf < 2; ++nf) {
                    acc[mf][nf] = MFMA16(a_h[mf], b_h[nf], acc[mf][nf]);
                    acc[mf][nf] = MFMA16(a_h[mf], b_l[nf], acc[mf][nf]);
                    acc[mf][nf] = MFMA16(a_l[mf], b_h[nf], acc[mf][nf]);
                }
        }
    }

#pragma unroll
    for (int mf = 0; mf < 2; ++mf)
#pragma unroll
        for (int nf = 0; nf < 2; ++nf) {
            const int n  = n0 + wn * 32 + nf * 16 + cl;
            const int mb = m0 + wm * 32 + mf * 16 + rg * 4;
            const float bv = bias[n];
            if (MODE == 0) {
#pragma unroll
                for (int j = 0; j < 4; ++j)
                    Ob[(size_t)(mb + j) * D_DIM + n] =
                        f2bf((acc[mf][nf][j] + bv) * scale);
            } else if (MODE == 1) {
                ushort4 pk;
                pk.x = f2bf(acc[mf][nf][0] + bv);
                pk.y = f2bf(acc[mf][nf][1] + bv);
                pk.z = f2bf(acc[mf][nf][2] + bv);
                pk.w = f2bf(acc[mf][nf][3] + bv);
                *(ushort4*)&Ob[(size_t)n * D_DIM + mb] = pk;   // Vt[n][m..m+3]
            } else {
#pragma unroll
                for (int j = 0; j < 4; ++j)
                    Of[(size_t)(mb + j) * D_DIM + n] = acc[mf][nf][j] + bv;
            }
        }
}

// ---------------------------------------------------------------------------
// FUSED QKV GEMM, bf16x3, hi|lo interleaved rows (conflict-free, round 7).
// Round-9: revert to single-buffer 2-phase (40 KB, 2 blocks/CU) + 2-D region
// XCD swizzle.
// ---------------------------------------------------------------------------
__global__ __launch_bounds__(512, 4) void gemm_qkv(
    const ush* __restrict__ xh, const ush* __restrict__ xl,
    const ush* __restrict__ Wqh, const ush* __restrict__ Wql,
    const ush* __restrict__ Wkh, const ush* __restrict__ Wkl,
    const ush* __restrict__ Wvh, const ush* __restrict__ Wvl,
    const float* __restrict__ bq, const float* __restrict__ bk,
    const float* __restrict__ bv, float qscale,
    ush* __restrict__ Qo, ush* __restrict__ Ko, ush* __restrict__ Vto)
{
    extern __shared__ char qsmem[];
    ush* As = (ush*)qsmem;                       // [128][64] hi|lo, 16 KB
    ush* Bs[3];
    Bs[0] = As + 8192;                           // [64][64] hi|lo, 8 KB each
    Bs[1] = As + 8192 + 4096;
    Bs[2] = As + 8192 + 8192;

    const int tid = threadIdx.x;
    const int l   = tid & 63;
    const int wid = tid >> 6;
    const int wm  = wid >> 1;      // 0..3
    const int wn  = wid & 1;       // 0..1
    const int cl  = l & 15;
    const int rg  = l >> 4;

    int m0, n0;
    region_swizzle(blockIdx.x, m0, n0);

    const ush* Wh[3] = {Wqh, Wkh, Wvh};
    const ush* Wl[3] = {Wql, Wkl, Wvl};

    v4f acc[3][2][2];
#pragma unroll
    for (int wg = 0; wg < 3; ++wg)
#pragma unroll
        for (int i = 0; i < 2; ++i)
#pragma unroll
            for (int j = 0; j < 2; ++j) acc[wg][i][j] = (v4f)0.f;

    for (int ks = 0; ks < D_DIM / 32; ++ks) {
        const int k0 = ks * 32;
        __syncthreads();
        // A: 1024 chunk-slots (128 rows x 8). phys slot p holds logical chunk
        // lc = (p&7)^(row&7); lc<4 -> hi k-chunk lc, lc>=4 -> lo k-chunk lc-4.
#pragma unroll
        for (int i = 0; i < 2; ++i) {
            const int p   = i * 512 + tid;
            const int row = p >> 3;
            const int lc  = (p & 7) ^ (row & 7);
            const ush* src = (lc < 4 ? xh : xl) +
                             (size_t)(m0 + row) * D_DIM + k0 + (lc & 3) * 8;
            gload_lds16(src, &As[p * 8]);
        }
        // B: 512 slots per weight (64 rows x 8)
        {
            const int p   = tid;
            const int row = p >> 3;
            const int lc  = (p & 7) ^ (row & 7);
            const size_t off = (size_t)(n0 + row) * D_DIM + k0 + (lc & 3) * 8;
#pragma unroll
            for (int wg = 0; wg < 3; ++wg)
                gload_lds16((lc < 4 ? Wh[wg] : Wl[wg]) + off, &Bs[wg][p * 8]);
        }
        __syncthreads();

        v8s a_h[2], a_l[2];
#pragma unroll
        for (int mf = 0; mf < 2; ++mf) {
            const int r = wm * 32 + mf * 16 + cl;
            a_h[mf] = *(const v8s*)&As[r * 64 + ((rg ^ (r & 7)) * 8)];
            a_l[mf] = *(const v8s*)&As[r * 64 + (((rg + 4) ^ (r & 7)) * 8)];
        }
#pragma unroll
        for (int wg = 0; wg < 3; ++wg) {
            v8s b_h[2], b_l[2];
#pragma unroll
            for (int nf = 0; nf < 2; ++nf) {
                const int r = wn * 32 + nf * 16 + cl;
                b_h[nf] = *(const v8s*)&Bs[wg][r * 64 + ((rg ^ (r & 7)) * 8)];
                b_l[nf] = *(const v8s*)&Bs[wg][r * 64 + (((rg + 4) ^ (r & 7)) * 8)];
            }
#pragma unroll
            for (int mf = 0; mf < 2; ++mf)
#pragma unroll
                for (int nf = 0; nf < 2; ++nf) {
                    acc[wg][mf][nf] = MFMA16(a_h[mf], b_h[nf], acc[wg][mf][nf]);
                    acc[wg][mf][nf] = MFMA16(a_h[mf], b_l[nf], acc[wg][mf][nf]);
                    acc[wg][mf][nf] = MFMA16(a_l[mf], b_h[nf], acc[wg][mf][nf]);
                }
        }
    }

    // epilogue: Q scaled row-major, K row-major, V transposed
#pragma unroll
    for (int mf = 0; mf < 2; ++mf)
#pragma unroll
        for (int nf = 0; nf < 2; ++nf) {
            const int n  = n0 + wn * 32 + nf * 16 + cl;
            const int mb = m0 + wm * 32 + mf * 16 + rg * 4;
            const float bvq = bq[n], bvk = bk[n], bvv = bv[n];
#pragma unroll
            for (int j = 0; j < 4; ++j) {
                Qo[(size_t)(mb + j) * D_DIM + n] =
                    f2bf((acc[0][mf][nf][j] + bvq) * qscale);
                Ko[(size_t)(mb + j) * D_DIM + n] =
                    f2bf(acc[1][mf][nf][j] + bvk);
            }
            ushort4 pk;
            pk.x = f2bf(acc[2][mf][nf][0] + bvv);
            pk.y = f2bf(acc[2][mf][nf][1] + bvv);
            pk.z = f2bf(acc[2][mf][nf][2] + bvv);
            pk.w = f2bf(acc[2][mf][nf][3] + bvv);
            *(ushort4*)&Vto[(size_t)n * D_DIM + mb] = pk;
        }
}

// ---------------------------------------------------------------------------
// Causal flash attention, bf16 MFMA, in-block KV split, swapped operands.
// LDS 64 KB (Ps overlaid on Ks[0:8KB]) -> 2 blocks/CU. (proven — unchanged)
// ---------------------------------------------------------------------------
__global__ __launch_bounds__(512, 4) void attn_fused(
    const ush* __restrict__ Qg, const ush* __restrict__ Kg,
    const ush* __restrict__ Vtg,
    ush* __restrict__ Yh, ush* __restrict__ Yl)
{
    extern __shared__ char smem[];
    const int b   = blockIdx.x;
    const int h   = b & 15;
    const int qt  = 31 - (b >> 4);       // descending: long blocks first
    const int q0  = qt * 64;
    const int tid = threadIdx.x;
    const int l   = tid & 63;
    const int wid = tid >> 6;
    const int grp = wid >> 2;            // 0 or 1
    const int w   = wid & 3;             // wave: q rows [w*16, w*16+16)
    const int cl  = l & 15;
    const int rg  = l >> 4;
    const int clx = cl & 7;
    const int tg  = tid & 255;

    char* gbase = smem + grp * 32768;
    ush* Ks = (ush*)gbase;               // [64][128] swz, 16 KB
    ush* Vs = (ush*)(gbase + 16384);     // [128][64] swz, 16 KB
    ush* Ps = Ks;                        // overlaid on Ks[0:8KB]

    const int split = (qt + 2) >> 1;
    const int iters = split;
    const int t0    = grp ? split : 0;
    const int tcnt  = grp ? (qt + 1 - split) : split;

    const int qrow = q0 + w * 16 + cl;

    v8s qf[4];
#pragma unroll
    for (int kf = 0; kf < 4; ++kf)
        qf[kf] = *(const v8s*)&Qg[(size_t)qrow * D_DIM + h * DHEAD + kf * 32 + rg * 8];

    v4f acc[8];
#pragma unroll
    for (int nf = 0; nf < 8; ++nf) acc[nf] = (v4f)0.f;
    float mrow = -INFINITY;
    float lsum = 0.f;

    auto stage = [&](int tile) {
#pragma unroll
        for (int i = 0; i < 4; ++i) {
            const int id = i * 256 + tg;
            const int kr = id >> 4, kc = id & 15;
            gload_lds16(&Kg[(size_t)(tile * 64 + kr) * D_DIM + h * DHEAD +
                            ((kc ^ (kr & 7)) * 8)], &Ks[id * 8]);
        }
#pragma unroll
        for (int i = 0; i < 4; ++i) {
            const int id = i * 256 + tg;
            const int vr = id >> 3, vc = id & 7;
            gload_lds16(&Vtg[(size_t)(h * DHEAD + vr) * D_DIM + tile * 64 +
                             ((vc ^ (vr & 7)) * 8)], &Vs[id * 8]);
        }
    };

    for (int t = 0; t < iters; ++t) {
        __syncthreads();                 // prev tile's Ks/Vs/Ps reads done
        if (t < tcnt) stage(t0 + t);
        __syncthreads();                 // staged data valid
        const bool act = (t < tcnt);
        const int tile = t0 + t;
        uint2 pk[4];
        if (act) {
            v4f st[4];
#pragma unroll
            for (int n = 0; n < 4; ++n) st[n] = (v4f)0.f;
            __builtin_amdgcn_s_setprio(1);
#pragma unroll
            for (int kf = 0; kf < 4; ++kf) {
#pragma unroll
                for (int n = 0; n < 4; ++n) {
                    const v8s kfr = *(const v8s*)&Ks[(n * 16 + cl) * 128 +
                                     (((kf * 4 + rg) ^ clx) * 8)];
                    st[n] = MFMA16(kfr, qf[kf], st[n]);
                }
            }
            __builtin_amdgcn_s_setprio(0);

            float sv[4][4];
            const bool dm = (tile == qt);
#pragma unroll
            for (int n = 0; n < 4; ++n)
#pragma unroll
                for (int jj = 0; jj < 4; ++jj) {
                    float v = st[n][jj];
                    if (dm && (tile * 64 + n * 16 + rg * 4 + jj > qrow))
                        v = -INFINITY;
                    sv[n][jj] = v;
                }
            float mx = sv[0][0];
#pragma unroll
            for (int n = 0; n < 4; ++n)
#pragma unroll
                for (int jj = 0; jj < 4; ++jj) mx = fmaxf(mx, sv[n][jj]);
            mx = fmaxf(mx, __shfl_xor(mx, 16));
            mx = fmaxf(mx, __shfl_xor(mx, 32));
            const float mnew = fmaxf(mrow, mx);

            float rs = 0.f;
#pragma unroll
            for (int n = 0; n < 4; ++n) {
                float p0 = exp2f(sv[n][0] - mnew);
                float p1 = exp2f(sv[n][1] - mnew);
                float p2 = exp2f(sv[n][2] - mnew);
                float p3 = exp2f(sv[n][3] - mnew);
                rs += (p0 + p1) + (p2 + p3);
                pk[n].x = pack2(f2bf(p0), f2bf(p1));
                pk[n].y = pack2(f2bf(p2), f2bf(p3));
            }
            rs += __shfl_xor(rs, 16);
            rs += __shfl_xor(rs, 32);

            const float corr = exp2f(mrow - mnew);
            lsum = lsum * corr + rs;
            mrow = mnew;
#pragma unroll
            for (int nf = 0; nf < 8; ++nf) acc[nf] *= corr;
        }
        __syncthreads();                 // all Ks reads done -> Ps may overwrite
        if (act) {
#pragma unroll
            for (int n = 0; n < 4; ++n)
                *(uint2*)&Ps[(w * 16 + cl) * 64 +
                             (((2 * n + (rg >> 1)) ^ clx) * 8) + (rg & 1) * 4] = pk[n];
            const int pr = w * 16 + cl;
            v8s pa[2];
            pa[0] = *(const v8s*)&Ps[pr * 64 + ((rg ^ clx) * 8)];
            pa[1] = *(const v8s*)&Ps[pr * 64 + (((4 + rg) ^ clx) * 8)];
            __builtin_amdgcn_s_setprio(1);
#pragma unroll
            for (int nf = 0; nf < 8; ++nf) {
#pragma unroll
                for (int kk = 0; kk < 2; ++kk) {
                    const v8s vb = *(const v8s*)&Vs[(nf * 16 + cl) * 64 +
                                    (((kk * 4 + rg) ^ clx) * 8)];
                    acc[nf] = MFMA16(vb, pa[kk], acc[nf]);
                }
            }
            __builtin_amdgcn_s_setprio(0);
        }
    }

    // ---- in-LDS merge of the two KV-half partials (lane-local in q) ----
    float* mAcc = (float*)smem;              // [64][132] fp32, 33792 B
    float* mML  = (float*)(smem + 33792);    // [64][2]

    const int lr = w * 16 + cl;
    __syncthreads();                         // all compute done
    if (grp == 1) {
#pragma unroll
        for (int nf = 0; nf < 8; ++nf)
            *(v4f*)&mAcc[lr * 132 + nf * 16 + rg * 4] = acc[nf];
        if (rg == 0) {
            mML[lr * 2]     = mrow;
            mML[lr * 2 + 1] = lsum;
        }
    }
    __syncthreads();
    if (grp == 0) {
        const float m1 = mML[lr * 2];
        const float l1 = mML[lr * 2 + 1];
        const float ms = fmaxf(mrow, m1);
        const float e0 = exp2f(mrow - ms);
        const float e1 = exp2f(m1 - ms);
        const float inv = 1.0f / (lsum * e0 + l1 * e1);
        const float s0 = e0 * inv, s1 = e1 * inv;
#pragma unroll
        for (int nf = 0; nf < 8; ++nf) {
            const v4f a1 = *(const v4f*)&mAcc[lr * 132 + nf * 16 + rg * 4];
            float y[4];
#pragma unroll
            for (int j = 0; j < 4; ++j) y[j] = acc[nf][j] * s0 + a1[j] * s1;
            ushort4 ph, pl;
            ush hh;
            hh = f2bf(y[0]); ph.x = hh; pl.x = f2bf(y[0] - bf2f(hh));
            hh = f2bf(y[1]); ph.y = hh; pl.y = f2bf(y[1] - bf2f(hh));
            hh = f2bf(y[2]); ph.z = hh; pl.z = f2bf(y[2] - bf2f(hh));
            hh = f2bf(y[3]); ph.w = hh; pl.w = f2bf(y[3] - bf2f(hh));
            const size_t o = (size_t)(q0 + lr) * D_DIM + h * DHEAD + nf * 16 + rg * 4;
            *(ushort4*)&Yh[o] = ph;
            *(ushort4*)&Yl[o] = pl;
        }
    }
}

// ---------------------------------------------------------------------------
extern "C" void kernel_launch(void* const* d_in, const int* in_sizes, int n_in,
                              void* d_out, int out_size, void* d_ws, size_t ws_size,
                              hipStream_t stream)
{
    const float* x  = (const float*)d_in[0];
    const float* Wq = (const float*)d_in[1];
    const float* bq = (const float*)d_in[2];
    const float* Wk = (const float*)d_in[3];
    const float* bk = (const float*)d_in[4];
    const float* Wv = (const float*)d_in[5];
    const float* bv = (const float*)d_in[6];
    const float* Wo = (const float*)d_in[7];
    const float* bo = (const float*)d_in[8];
    float* out = (float*)d_out;

    const size_t mat = (size_t)T_DIM * D_DIM;
    // 1/sqrt(128) * log2(e): attention runs in exp2 domain
    const float qscale = 0.08838834764831845f * 1.4426950408889634f;

    const int attn_lds = 65536;
    hipFuncSetAttribute((const void*)attn_fused,
                        hipFuncAttributeMaxDynamicSharedMemorySize, attn_lds);
    hipFuncSetAttribute((const void*)gemm_qkv,
                        hipFuncAttributeMaxDynamicSharedMemorySize, 40960);

    const size_t need_fused = 13 * mat * sizeof(ush);   // 109.1 MB

    if (ws_size >= need_fused) {
        // ---------------- fused path: 4 dispatches ----------------
        ush* xh  = (ush*)d_ws;
        ush* xl  = xh  + mat;
        ush* Qh  = xl  + mat;
        ush* Kh  = Qh  + mat;
        ush* Vth = Kh  + mat;
        ush* Wqh = Vth + mat;
        ush* Wql = Wqh + mat;
        ush* Wkh = Wql + mat;
        ush* Wkl = Wkh + mat;
        ush* Wvh = Wkl + mat;
        ush* Wvl = Wvh + mat;
        ush* Woh = Wvl + mat;
        ush* Wol = Woh + mat;
        ush* Yh  = xh;   // x dead after gemm_qkv
        ush* Yl  = xl;

        Split5Args sa;
        sa.s[0] = x;  sa.h[0] = xh;  sa.l[0] = xl;
        sa.s[1] = Wq; sa.h[1] = Wqh; sa.l[1] = Wql;
        sa.s[2] = Wk; sa.h[2] = Wkh; sa.l[2] = Wkl;
        sa.s[3] = Wv; sa.h[3] = Wvh; sa.l[3] = Wvl;
        sa.s[4] = Wo; sa.h[4] = Woh; sa.l[4] = Wol;
        split5<<<dim3(mat / 2048, 5), 256, 0, stream>>>(sa);

        gemm_qkv<<<512, 512, 40960, stream>>>(
            xh, xl, Wqh, Wql, Wkh, Wkl, Wvh, Wvl, bq, bk, bv, qscale,
            Qh, Kh, Vth);

        attn_fused<<<512, 512, attn_lds, stream>>>(Qh, Kh, Vth, Yh, Yl);

        gemm_x3<2><<<512, 512, 0, stream>>>(Yh, Yl, Woh, Wol, bo, 1.0f,
                                            nullptr, out);
    } else {
        // ---------------- fallback: proven round-5 sequence ----------------
        ush* xh  = (ush*)d_ws;
        ush* xl  = xh + mat;
        ush* Qh  = xl + mat;
        ush* Kh  = Qh + mat;
        ush* Vth = Kh + mat;
        ush* Wh  = Vth + mat;
        ush* Wl  = Wh + mat;
        ush* Yh  = xh;
        ush* Yl  = xl;

        split_x<<<mat / 2048, 256, 0, stream>>>(x, xh, xl);

        split_x<<<mat / 2048, 256, 0, stream>>>(Wq, Wh, Wl);
        gemm_x3<0><<<512, 512, 0, stream>>>(xh, xl, Wh, Wl, bq, qscale, Qh, nullptr);
        split_x<<<mat / 2048, 256, 0, stream>>>(Wk, Wh, Wl);
        gemm_x3<0><<<512, 512, 0, stream>>>(xh, xl, Wh, Wl, bk, 1.0f, Kh, nullptr);
        split_x<<<mat / 2048, 256, 0, stream>>>(Wv, Wh, Wl);
        gemm_x3<1><<<512, 512, 0, stream>>>(xh, xl, Wh, Wl, bv, 1.0f, Vth, nullptr);

        attn_fused<<<512, 512, attn_lds, stream>>>(Qh, Kh, Vth, Yh, Yl);

        split_x<<<mat / 2048, 256, 0, stream>>>(Wo, Wh, Wl);
        gemm_x3<2><<<512, 512, 0, stream>>>(Yh, Yl, Wh, Wl, bo, 1.0f, nullptr, out);
    }
}